// Round 11
// baseline (275.544 us; speedup 1.0000x reference)
//
#include <hip/hip_runtime.h>
#include <hip/hip_bf16.h>
#include <stdint.h>

// Problem constants: B=4, S=2048, D=1024, H=1024, heads=16, d_k=64.
// Pipeline: fused cast->bf16; fused QKV GEMM (128x256-tile 4-phase
// counted-vmcnt, grid 768 = 3 balanced rounds, XCD chunks of 96);
// flash attention (PV lagged one tile, per-wave swizzled LDS P-bounce,
// zero-C QK MFMA, MFMA row-sums, V triple-buffered, setprio on merged MFMA
// cluster; R11: v_cvt_pk_bf16_f32 packs via the DOCUMENTED HIP intrinsic
// __float22bfloat162_rn (R4's failure was hand-asm with guessed operand
// order; R10's compile failure was bit_cast on non-trivially-copyable
// __hip_bfloat162 -> use memcpy) + pointer-increment staging addresses);
// out GEMM (128x256 4-phase, unchanged).
// LDS tiles XOR-swizzled (granule g of row r at g^(r&7)) -> conflict-free b128.

using bf16x8 = __attribute__((ext_vector_type(8))) short;   // 8 bf16 = 4 VGPRs
using f32x4  = __attribute__((ext_vector_type(4))) float;   // MFMA C/D frag

#define QSCALE 0.18033688f  // 1/sqrt(64) * log2(e): scores come out log2-scaled -> exp2

__device__ __forceinline__ unsigned short f2bf(float f) {
    unsigned u = __builtin_bit_cast(unsigned, f);
    u += 0x7fffu + ((u >> 16) & 1u);          // RNE
    return (unsigned short)(u >> 16);
}

// pack two f32 -> two bf16 in one dword: round-to-nearest (ties away) + v_perm
__device__ __forceinline__ unsigned pack2bf(float f0, float f1) {
    unsigned u0 = __builtin_bit_cast(unsigned, f0) + 0x8000u;
    unsigned u1 = __builtin_bit_cast(unsigned, f1) + 0x8000u;
    return __builtin_amdgcn_perm(u1, u0, 0x07060302);  // {hi16(u1),hi16(u0)}
}

// pack two f32 -> two bf16 via v_cvt_pk_bf16_f32 (documented HIP intrinsic;
// .x -> low16, .y -> high16 == pack2bf placement, RNE rounding).
// memcpy (not bit_cast): __hip_bfloat162 is not trivially copyable.
__device__ __forceinline__ unsigned pkbf(float a, float b) {
    __hip_bfloat162 h = __float22bfloat162_rn(make_float2(a, b));
    unsigned r;
    __builtin_memcpy(&r, &h, 4);
    return r;
}

// async global->LDS, 16B per lane; LDS dest = wave-uniform base + lane*16
__device__ __forceinline__ void gld16(const void* g, void* l) {
    void* gnc = (void*)g;
    __builtin_amdgcn_global_load_lds((__attribute__((address_space(1))) void*)gnc,
                                     (__attribute__((address_space(3))) void*)l,
                                     16, 0, 0);
}

// swizzled LDS short-offset for (row R, 16B-granule g) in a 64-short-row tile
__device__ __forceinline__ int swz(int R, int g) {
    return R * 64 + ((g ^ (R & 7)) << 3);
}

// ---------------------------------------------------------------- fused casts
__global__ void castall(const float* __restrict__ X, const float* __restrict__ Wq,
                        const float* __restrict__ Wk, const float* __restrict__ Wv,
                        const float* __restrict__ Wo, unsigned short* __restrict__ Xb,
                        unsigned short* __restrict__ Wqkvb, unsigned short* __restrict__ Wob) {
    const int bx = blockIdx.x;
    const float* src; unsigned short* dst; int idx;
    if (bx < 8192) { src = X; dst = Xb; idx = bx * 256 + threadIdx.x; }
    else {
        const int r = bx - 8192, w = r >> 10;
        idx = (r & 1023) * 256 + threadIdx.x;
        src = (w == 0) ? Wq : (w == 1) ? Wk : (w == 2) ? Wv : Wo;
        dst = (w == 3) ? Wob : Wqkvb + (size_t)w * 1048576;
    }
    float4 v = ((const float4*)src)[idx];
    ((uint2*)dst)[idx] = make_uint2(pack2bf(v.x, v.y), pack2bf(v.z, v.w));
}

// ---------------------------------------------------------------- fused QKV GEMM
// A: (8192,1024) bf16. Wqkv: 3 stacked (1024,1024) bf16 = one (3072,1024).
// 128x256 tile (4-phase counted-vmcnt), BK=64, 8 waves (2Mx4N, per-wave
// 64x64, acc[4][4]), 96 KiB LDS dbuf. Grid 768 = 3 balanced rounds.
// Per K-tile t: ph0 read B(8)+A(mf0), stage A(t+1)->b^1; ph1 read A(mf1),
// stage B0(t+2)->b; ph2 read A(mf2), stage B1(t+2)->b; ph3 read A(mf3),
// vmcnt(4). Each phase: barrier; setprio(1); 8 MFMA; setprio(0); barrier.
// XCD swizzle: chunks of 96. Epilogue: Q scaled by QSCALE; V transposed
// per head: Vt[(b*1024+n)*2048+s].
__global__ __launch_bounds__(512, 2) void gemm_qkv(const unsigned short* __restrict__ A,
                                                   const unsigned short* __restrict__ Wqkv,
                                                   const float* __restrict__ bq,
                                                   const float* __restrict__ bk,
                                                   const float* __restrict__ bv,
                                                   unsigned short* __restrict__ Qb,
                                                   unsigned short* __restrict__ Kb,
                                                   unsigned short* __restrict__ Vt) {
    __shared__ alignas(16) unsigned short smem[49152];   // 96 KiB: [buf][A 128x64|B 256x64]

    const int tid  = threadIdx.x;
    const int lane = tid & 63;
    const int w    = tid >> 6;
    const int quad = lane >> 4;
    const int l15  = lane & 15;
    const int lr   = lane >> 3;
    const int lcs  = (((lane & 7) ^ lr) << 3);
    const int wm   = w >> 2;            // 0..1 (M, 64 rows each)
    const int wn   = w & 3;             // 0..3 (N, 64 cols each)

    // XCD swizzle: 768 blocks, 768%8==0 -> wg=(orig&7)*96+orig>>3.
    int wg = blockIdx.x;
    wg = (wg & 7) * 96 + (wg >> 3);
    const int nn = wg % 12, mm = wg / 12;
    const int col0 = nn * 256;           // within 3072 (QKV stacked)
    const int row0 = mm * 128;           // token row

    const unsigned short* aS = A    + (size_t)(row0 + w * 16 + lr) * 1024 + lcs;
    const unsigned short* bS = Wqkv + (size_t)(col0 + w * 16 + lr) * 1024 + lcs;
    const int dstW = w * 1024;

#define STG_AQ(t_, b_)                                                                  \
    { const unsigned short* s_ = aS + (t_) * 64;                                        \
      gld16(s_,            &smem[(b_) * 24576 + dstW]);                                 \
      gld16(s_ + 8 * 1024, &smem[(b_) * 24576 + dstW + 512]); }
#define STG_BQ(t_, h_, b_)                                                              \
    { const unsigned short* s_ = bS + (size_t)(h_) * 131072 + (t_) * 64;                \
      gld16(s_,            &smem[(b_) * 24576 + 8192 + (h_) * 8192 + dstW]);            \
      gld16(s_ + 8 * 1024, &smem[(b_) * 24576 + 8192 + (h_) * 8192 + dstW + 512]); }

    f32x4 acc[4][4];
#pragma unroll
    for (int i = 0; i < 4; i++)
#pragma unroll
        for (int j = 0; j < 4; j++) acc[i][j] = f32x4{0.f, 0.f, 0.f, 0.f};

    // prologue: tile0 fully (A,B0,B1) + tile1's B halves; wait tile0.
    STG_AQ(0, 0) STG_BQ(0, 0, 0) STG_BQ(0, 1, 0)
    STG_BQ(1, 0, 1) STG_BQ(1, 1, 1)
    asm volatile("s_waitcnt vmcnt(4)" ::: "memory");
    __builtin_amdgcn_s_barrier();

    for (int t = 0; t < 16; ++t) {
        const int b = t & 1;
        unsigned short* bufA = smem + b * 24576;
        unsigned short* bufB = bufA + 8192;
        bf16x8 bfr[4][2];
#pragma unroll
        for (int p = 0; p < 4; ++p) {
            bf16x8 afr[2];
            if (p == 0) {
#pragma unroll
                for (int nf = 0; nf < 4; ++nf)
#pragma unroll
                    for (int kx = 0; kx < 2; ++kx)
                        bfr[nf][kx] = *(const bf16x8*)&bufB[swz(wn * 64 + nf * 16 + l15, kx * 4 + quad)];
            }
#pragma unroll
            for (int kx = 0; kx < 2; ++kx)
                afr[kx] = *(const bf16x8*)&bufA[swz(wm * 64 + p * 16 + l15, kx * 4 + quad)];

            if (p == 0)      { if (t < 15) STG_AQ(t + 1, b ^ 1) }
            else if (p == 1) { if (t < 14) STG_BQ(t + 2, 0, b) }
            else if (p == 2) { if (t < 14) STG_BQ(t + 2, 1, b) }
            else {
                if (t < 14)      { asm volatile("s_waitcnt vmcnt(4)" ::: "memory"); }
                else if (t == 14){ asm volatile("s_waitcnt vmcnt(0)" ::: "memory"); }
            }
            __builtin_amdgcn_s_barrier();
            __builtin_amdgcn_s_setprio(1);
#pragma unroll
            for (int kx = 0; kx < 2; ++kx)
#pragma unroll
                for (int nf = 0; nf < 4; ++nf)
                    acc[p][nf] = __builtin_amdgcn_mfma_f32_16x16x32_bf16(
                        afr[kx], bfr[nf][kx], acc[p][nf], 0, 0, 0);
            __builtin_amdgcn_s_setprio(0);
            __builtin_amdgcn_s_barrier();
        }
    }
#undef STG_AQ
#undef STG_BQ

    // ---- epilogue: bounce through dead staging LDS for coalesced b128 stores
    const int nb   = col0 >> 10;             // 0=Q 1=K 2=V
    const int colq = col0 & 1023;
    const float* bias = (nb == 0) ? bq : (nb == 1) ? bk : bv;

    if (nb != 2) {
        const float sc = (nb == 0) ? QSCALE : 1.0f;
        unsigned short* C = (nb == 0) ? Qb : Kb;
        // OT[128][264]: all 8 waves write their 64x64 quadrants
#pragma unroll
        for (int mf = 0; mf < 4; ++mf)
#pragma unroll
            for (int nf = 0; nf < 4; ++nf) {
                const int ct  = wn * 64 + nf * 16 + l15;
                const float bvv = bias[colq + ct];
                const int rt  = wm * 64 + mf * 16 + quad * 4;
#pragma unroll
                for (int r = 0; r < 4; ++r)
                    smem[(rt + r) * 264 + ct] = f2bf((acc[mf][nf][r] + bvv) * sc);
            }
        __syncthreads();
        const int rr = tid >> 2, qq = tid & 3;
        unsigned short* gdst = C + (size_t)(row0 + rr) * 1024 + colq + qq * 64;
#pragma unroll
        for (int j = 0; j < 8; ++j)
            *(bf16x8*)(gdst + j * 8) = *(const bf16x8*)&smem[rr * 264 + qq * 64 + j * 8];
    } else {
        const int bb = row0 >> 11, s0 = row0 & 2047;
        // OT[256 d][136 s]: transposed tile (s range = 128 rows)
#pragma unroll
        for (int mf = 0; mf < 4; ++mf)
#pragma unroll
            for (int nf = 0; nf < 4; ++nf) {
                const int ct  = wn * 64 + nf * 16 + l15;
                const float bvv = bias[colq + ct];
                const int st  = wm * 64 + mf * 16 + quad * 4;
                *(uint2*)&smem[ct * 136 + st] =
                    make_uint2(pack2bf(acc[mf][nf][0] + bvv, acc[mf][nf][1] + bvv),
                               pack2bf(acc[mf][nf][2] + bvv, acc[mf][nf][3] + bvv));
            }
        __syncthreads();
        const int c = tid >> 1, hs = tid & 1;
        unsigned short* gdst = Vt + ((size_t)(bb * 1024 + colq + c)) * 2048 + s0 + hs * 64;
#pragma unroll
        for (int j = 0; j < 8; ++j)
            *(bf16x8*)(gdst + j * 8) = *(const bf16x8*)&smem[c * 136 + hs * 64 + j * 8];
    }
}

// ---------------------------------------------------------------- out GEMM (f32 out)
// gemm 4-phase counted-vmcnt structure. BM=128 x BN=256, BK=64, 8 waves
// (2Mx4N, per-wave 64x64, acc[4][4]), 96 KiB LDS dbuf, grid 256 = 1 block/CU.
__global__ __launch_bounds__(512, 2) void gemm_out(const unsigned short* __restrict__ A,
                                                   const unsigned short* __restrict__ W,
                                                   const float* __restrict__ bias,
                                                   float* __restrict__ C) {
    __shared__ alignas(16) unsigned short smem[49152];   // 96 KiB: [buf][A 128x64|B 256x64]

    const int tid  = threadIdx.x;
    const int lane = tid & 63;
    const int w    = tid >> 6;
    const int quad = lane >> 4;
    const int l15  = lane & 15;
    const int lr   = lane >> 3;
    const int lcs  = (((lane & 7) ^ lr) << 3);
    const int wm   = w >> 2;            // 0..1 (M, 64 rows each)
    const int wn   = w & 3;             // 0..3 (N, 64 cols each)

    // XCD swizzle: 256 blocks -> wg=(orig&7)*32+orig>>3; XCD owns 8 M-panels.
    int wg = blockIdx.x;
    wg = (wg & 7) * 32 + (wg >> 3);
    const int col0 = (wg & 3) * 256;     // N tile (4)
    const int row0 = (wg >> 2) * 128;    // M tile (64)

    const unsigned short* aS = A + (size_t)(row0 + w * 16 + lr) * 1024 + lcs;
    const unsigned short* bS = W + (size_t)(col0 + w * 16 + lr) * 1024 + lcs;
    const int dstW = w * 1024;

#define STG_AO(t_, b_)                                                                  \
    { const unsigned short* s_ = aS + (t_) * 64;                                        \
      gld16(s_,            &smem[(b_) * 24576 + dstW]);                                 \
      gld16(s_ + 8 * 1024, &smem[(b_) * 24576 + dstW + 512]); }
#define STG_BO(t_, h_, b_)                                                              \
    { const unsigned short* s_ = bS + (size_t)(h_) * 131072 + (t_) * 64;                \
      gld16(s_,            &smem[(b_) * 24576 + 8192 + (h_) * 8192 + dstW]);            \
      gld16(s_ + 8 * 1024, &smem[(b_) * 24576 + 8192 + (h_) * 8192 + dstW + 512]); }

    f32x4 acc[4][4];
#pragma unroll
    for (int i = 0; i < 4; i++)
#pragma unroll
        for (int j = 0; j < 4; j++) acc[i][j] = f32x4{0.f, 0.f, 0.f, 0.f};

    // prologue: tile0 fully (A,B0,B1) + tile1's B halves; wait tile0.
    STG_AO(0, 0) STG_BO(0, 0, 0) STG_BO(0, 1, 0)
    STG_BO(1, 0, 1) STG_BO(1, 1, 1)
    asm volatile("s_waitcnt vmcnt(4)" ::: "memory");
    __builtin_amdgcn_s_barrier();

    for (int t = 0; t < 16; ++t) {
        const int b = t & 1;
        unsigned short* bufA = smem + b * 24576;
        unsigned short* bufB = bufA + 8192;
        bf16x8 bfr[4][2];
#pragma unroll
        for (int p = 0; p < 4; ++p) {
            bf16x8 afr[2];
            if (p == 0) {
#pragma unroll
                for (int nf = 0; nf < 4; ++nf)
#pragma unroll
                    for (int kx = 0; kx < 2; ++kx)
                        bfr[nf][kx] = *(const bf16x8*)&bufB[swz(wn * 64 + nf * 16 + l15, kx * 4 + quad)];
            }
#pragma unroll
            for (int kx = 0; kx < 2; ++kx)
                afr[kx] = *(const bf16x8*)&bufA[swz(wm * 64 + p * 16 + l15, kx * 4 + quad)];

            if (p == 0)      { if (t < 15) STG_AO(t + 1, b ^ 1) }
            else if (p == 1) { if (t < 14) STG_BO(t + 2, 0, b) }
            else if (p == 2) { if (t < 14) STG_BO(t + 2, 1, b) }
            else {
                if (t < 14)      { asm volatile("s_waitcnt vmcnt(4)" ::: "memory"); }
                else if (t == 14){ asm volatile("s_waitcnt vmcnt(0)" ::: "memory"); }
            }
            __builtin_amdgcn_s_barrier();
            __builtin_amdgcn_s_setprio(1);
#pragma unroll
            for (int kx = 0; kx < 2; ++kx)
#pragma unroll
                for (int nf = 0; nf < 4; ++nf)
                    acc[p][nf] = __builtin_amdgcn_mfma_f32_16x16x32_bf16(
                        afr[kx], bfr[nf][kx], acc[p][nf], 0, 0, 0);
            __builtin_amdgcn_s_setprio(0);
            __builtin_amdgcn_s_barrier();
        }
    }
#undef STG_AO
#undef STG_BO

#pragma unroll
    for (int mf = 0; mf < 4; ++mf) {
#pragma unroll
        for (int nf = 0; nf < 4; ++nf) {
            const int col   = col0 + wn * 64 + nf * 16 + l15;
            const float bvv = bias[col];
            const int rbase = row0 + wm * 64 + mf * 16 + quad * 4;
#pragma unroll
            for (int r = 0; r < 4; r++)
                C[(size_t)(rbase + r) * 1024 + col] = acc[mf][nf][r] + bvv;
        }
    }
}

// ---------------------------------------------------------------- flash attention
// Q, K: (B*S, 1024) bf16; Q pre-scaled by QSCALE (fold softmax scale + log2e).
// Vt: (B*1024, 2048) bf16. Ctx out: (B*S, 1024) bf16.
// Block: 256 q-rows of one (b,h), 8 waves (512 thr); wave owns 32 q-rows.
// 32 k-tiles of 64. Pipelined loop: per iteration QK(kt) -> PV(kt-1) ->
// exp/pack(kt). PV's pa reads precede pw writes in program order; its MFMAs
// issue under QK's result latency; exp2 then finds St complete. V is
// TRIPLE-buffered. K stays dbuf. Row-sums via MFMA (Osum += P @ ones).
// Zero-C QK MFMA; hoisted offsets; setprio(1) over merged MFMA cluster.
// R11: single-inst packs (v_cvt_pk via __float22bfloat162_rn + memcpy) +
// pointer-increment staging addresses (VALU is the critical pipe: 48.7%).
__global__ __launch_bounds__(512, 4) void attn(const unsigned short* __restrict__ Q,
                                               const unsigned short* __restrict__ K,
                                               const unsigned short* __restrict__ Vt,
                                               unsigned short* __restrict__ Ctx) {
    __shared__ alignas(16) unsigned short Kl[2][4096];     // K dbuf (16KB), swizzled
    __shared__ alignas(16) unsigned short Vl[3][4096];     // V tbuf (24KB), swizzled
    __shared__ alignas(16) unsigned short Pl[8][2048];     // per-wave [32 q][64 k] swz (32KB)

    const int tid  = threadIdx.x;
    const int lane = tid & 63;
    const int wave = tid >> 6;        // 0..7
    const int quad = lane >> 4;
    const int l15  = lane & 15;
    const int lr   = lane >> 3;
    const int lcs  = (((lane & 7) ^ lr) << 3);

    const int qt = blockIdx.x, h = blockIdx.y, b = blockIdx.z;
    const int q0 = qt * 256;
    const size_t tokbase = (size_t)b * 2048;

    // hoisted swizzled LDS offsets: frag (nt,kx) at [nt*1024 + lo(kx)];
    // P A-frag (mt,kx) at [mt*1024 + lo(kx)] in the wave's Pl tile.
    const int lo0 = l15 * 64 + (((quad    ) ^ (l15 & 7)) << 3);
    const int lo1 = l15 * 64 + (((quad + 4) ^ (l15 & 7)) << 3);
    // P write offset for k-block nt (b64 = 4 shorts at col nt*16+quad*4):
    int pwoff[4];
#pragma unroll
    for (int nt = 0; nt < 4; ++nt)
        pwoff[nt] = l15 * 64 + ((((nt << 1) | (quad >> 1)) ^ (l15 & 7)) << 3) + ((quad & 1) << 2);
    unsigned short* pw = &Pl[wave][0];

    // staging source base pointers (advance by constant per kt)
    const int rr = wave * 8 + lr;
    const unsigned short* kp = K  + (tokbase + rr) * 1024 + h * 64 + lcs;
    const unsigned short* vp = Vt + ((size_t)(b * 1024 + h * 64 + rr)) * 2048 + lcs;

    bf16x8 qa[2][2];
#pragma unroll
    for (int mt = 0; mt < 2; ++mt)
#pragma unroll
        for (int kx = 0; kx < 2; ++kx)
            qa[mt][kx] = *(const bf16x8*)(Q + (tokbase + q0 + wave * 32 + mt * 16 + l15) * 1024 +
                                          h * 64 + kx * 32 + quad * 8);

    f32x4 O[2][4], Osum[2];
#pragma unroll
    for (int mt = 0; mt < 2; ++mt) {
#pragma unroll
        for (int nt = 0; nt < 4; ++nt) O[mt][nt] = f32x4{0.f, 0.f, 0.f, 0.f};
        Osum[mt] = f32x4{0.f, 0.f, 0.f, 0.f};
    }
    const f32x4 z4 = {0.f, 0.f, 0.f, 0.f};   // persistent zero C-operand
    const bf16x8 vones = {16256, 16256, 16256, 16256, 16256, 16256, 16256, 16256};  // bf16 1.0

#define AT_STAGE(kt_, kb_, vbuf_)                                                               \
    {                                                                                           \
        gld16(kp + (size_t)(kt_) * 65536, &Kl[kb_][wave * 512]);                                \
        gld16(vp + (kt_) * 64,            &Vl[vbuf_][wave * 512]);                              \
    }

// QK(kt): S^T = K @ Q^T  (C layout: row=quad*4+r is K-COL, col=lane&15 is Q-ROW)
#define QK_BLOCK(kbase_)                                                                        \
    {                                                                                           \
        bf16x8 kb[4];                                                                           \
        _Pragma("unroll") for (int nt = 0; nt < 4; ++nt)                                        \
            kb[nt] = *(const bf16x8*)&(kbase_)[lo0 + nt * 1024];                                \
        _Pragma("unroll") for (int nt = 0; nt < 4; ++nt)                                        \
            _Pragma("unroll") for (int mt = 0; mt < 2; ++mt)                                    \
                St[nt][mt] = __builtin_amdgcn_mfma_f32_16x16x32_bf16(kb[nt], qa[mt][0], z4, 0, 0, 0); \
        _Pragma("unroll") for (int nt = 0; nt < 4; ++nt)                                        \
            kb[nt] = *(const bf16x8*)&(kbase_)[lo1 + nt * 1024];                                \
        _Pragma("unroll") for (int nt = 0; nt < 4; ++nt)                                        \
            _Pragma("unroll") for (int mt = 0; mt < 2; ++mt)                                    \
                St[nt][mt] = __builtin_amdgcn_mfma_f32_16x16x32_bf16(kb[nt], qa[mt][1], St[nt][mt], 0, 0, 0); \
    }

// PV(prev): O += P @ V ; Osum += P @ ones  (pa from pw, vb from vbase_)
#define PV_BLOCK(vbase_)                                                                        \
    _Pragma("unroll") for (int kx = 0; kx < 2; ++kx) {                                          \
        bf16x8 pa[2], vb[4];                                                                    \
        _Pragma("unroll") for (int mt = 0; mt < 2; ++mt)                                        \
            pa[mt] = *(const bf16x8*)&pw[mt * 1024 + (kx ? lo1 : lo0)];                         \
        _Pragma("unroll") for (int nt = 0; nt < 4; ++nt)                                        \
            vb[nt] = *(const bf16x8*)&(vbase_)[(kx ? lo1 : lo0) + nt * 1024];                   \
        _Pragma("unroll") for (int mt = 0; mt < 2; ++mt) {                                      \
            _Pragma("unroll") for (int nt = 0; nt < 4; ++nt)                                    \
                O[mt][nt] = __builtin_amdgcn_mfma_f32_16x16x32_bf16(pa[mt], vb[nt], O[mt][nt], 0, 0, 0); \
            Osum[mt] = __builtin_amdgcn_mfma_f32_16x16x32_bf16(pa[mt], vones, Osum[mt], 0, 0, 0); \
        }                                                                                       \
    }

// exp/pack(kt) -> per-wave swizzled P tile (single-inst cvt_pk packs)
#define SM_BLOCK                                                                                \
    _Pragma("unroll") for (int mt = 0; mt < 2; ++mt) {                                          \
        _Pragma("unroll") for (int nt = 0; nt < 4; ++nt) {                                      \
            float p0 = __builtin_amdgcn_exp2f(St[nt][mt][0]);                                   \
            float p1 = __builtin_amdgcn_exp2f(St[nt][mt][1]);                                   \
            float p2 = __builtin_amdgcn_exp2f(St[nt][mt][2]);                                   \
            float p3 = __builtin_amdgcn_exp2f(St[nt][mt][3]);                                   \
            *(uint2*)&pw[mt * 1024 + pwoff[nt]] =                                               \
                make_uint2(pkbf(p0, p1), pkbf(p2, p3));                                         \
        }                                                                                       \
    }

    f32x4 St[4][2];

    // prologue: stage tile0; publish; stage tile1; QK(0)+softmax(0)
    AT_STAGE(0, 0, 0)
    __syncthreads();
    AT_STAGE(1, 1, 1)
    QK_BLOCK(&Kl[0][0])
    SM_BLOCK

    int vprev = 0;   // (kt-1)%3
    int vnext = 2;   // (kt+1)%3
    for (int kt = 1; kt < 32; ++kt) {
        __syncthreads();                 // publishes tile kt; drains prev DS reads
        if (kt < 31) AT_STAGE(kt + 1, (kt + 1) & 1, vnext)
        const unsigned short* kbase = &Kl[kt & 1][0];
        const unsigned short* vbase = &Vl[vprev][0];
        __builtin_amdgcn_s_setprio(1);
        QK_BLOCK(kbase)                  // MFMA: St(kt)
        PV_BLOCK(vbase)                  // MFMA: O += P(kt-1)@V(kt-1); pa reads precede pw writes
        __builtin_amdgcn_s_setprio(0);
        SM_BLOCK                         // VALU: exp/pack(kt) -> pw (St complete by now)
        vprev = (vprev == 2) ? 0 : vprev + 1;
        vnext = (vnext == 2) ? 0 : vnext + 1;
    }
    // epilogue: PV(31) -- P in pw (own wave), V(31) in Vl[vprev=1] (published @kt=31)
    PV_BLOCK(&Vl[vprev][0])

#undef AT_STAGE
#undef QK_BLOCK
#undef PV_BLOCK
#undef SM_BLOCK

    // normalize + store ctx; O C-layout rows = quad*4+r match Osum rows exactly
#pragma unroll
    for (int mt = 0; mt < 2; ++mt) {
#pragma unroll
        for (int r = 0; r < 4; ++r) {
            const float inv = 1.0f / Osum[mt][r];
            const int row   = q0 + wave * 32 + mt * 16 + quad * 4 + r;
            const size_t base = (tokbase + row) * 1024 + h * 64;
#pragma unroll
            for (int nt = 0; nt < 4; ++nt)
                Ctx[base + nt * 16 + l15] = f2bf(O[mt][nt][r] * inv);
        }
    }
}

// ---------------------------------------------------------------- launch
extern "C" void kernel_launch(void* const* d_in, const int* in_sizes, int n_in,
                              void* d_out, int out_size, void* d_ws, size_t ws_size,
                              hipStream_t stream) {
    (void)in_sizes; (void)n_in; (void)out_size; (void)ws_size;
    const float* X  = (const float*)d_in[0];
    const float* Wq = (const float*)d_in[1];
    const float* bq = (const float*)d_in[2];
    const float* Wk = (const float*)d_in[3];
    const float* bk = (const float*)d_in[4];
    const float* Wv = (const float*)d_in[5];
    const float* bv = (const float*)d_in[6];
    const float* Wo = (const float*)d_in[7];
    const float* bo = (const float*)d_in[8];

    char* ws = (char*)d_ws;
    unsigned short* Xb    = (unsigned short*)(ws);                        // 16 MB (aliased as Ctx)
    unsigned short* Qb    = (unsigned short*)(ws + (size_t)16 * 1048576); // 16 MB
    unsigned short* Kb    = (unsigned short*)(ws + (size_t)32 * 1048576); // 16 MB
    unsigned short* Vt    = (unsigned short*)(ws + (size_t)48 * 1048576); // 16 MB
    unsigned short* Wqkvb = (unsigned short*)(ws + (size_t)64 * 1048576); // 6 MB
    unsigned short* Wob   = (unsigned short*)(ws + (size_t)70 * 1048576); // 2 MB
    unsigned short* Ctx   = Xb;  // X dead after QKV GEMM (stream-ordered)

    castall<<<dim3(12288), 256, 0, stream>>>(X, Wq, Wk, Wv, Wo, Xb, Wqkvb, Wob);
    gemm_qkv<<<dim3(768), 512, 0, stream>>>(Xb, Wqkvb, bq, bk, bv, Qb, Kb, Vt);
    attn<<<dim3(8, 16, 4), 512, 0, stream>>>(Qb, Kb, Vt, Ctx);
    gemm_out<<<dim3(256), 512, 0, stream>>>(Ctx, Wob, bo, (float*)d_out);
}

// Round 12
// 273.958 us; speedup vs baseline: 1.0058x; 1.0058x over previous
//
#include <hip/hip_runtime.h>
#include <hip/hip_bf16.h>
#include <stdint.h>

// Problem constants: B=4, S=2048, D=1024, H=1024, heads=16, d_k=64.
// Pipeline: fused cast->bf16; fused QKV GEMM (128x256-tile 4-phase
// counted-vmcnt, grid 768 = 3 balanced rounds, XCD chunks of 96);
// flash attention (PV lagged one tile, per-wave swizzled LDS P-bounce,
// zero-C QK MFMA, MFMA row-sums, V triple-buffered, setprio on merged MFMA
// cluster, cvt_pk packs; R12: XCD-locality grid -- the 8 q-tile blocks
// sharing one (b,h)'s K/V panels are emitted 8-apart in blockIdx so they
// land on ONE XCD (round-robin dispatch), all co-resident (2 blocks/CU):
// K/V becomes L2-hit for 7 of 8 readers. R11 FETCH was 141MB vs 48MB unique
// = 3x amplification from round-robin spreading the sharers);
// out GEMM (128x256 4-phase, unchanged).
// LDS tiles XOR-swizzled (granule g of row r at g^(r&7)) -> conflict-free b128.

using bf16x8 = __attribute__((ext_vector_type(8))) short;   // 8 bf16 = 4 VGPRs
using f32x4  = __attribute__((ext_vector_type(4))) float;   // MFMA C/D frag

#define QSCALE 0.18033688f  // 1/sqrt(64) * log2(e): scores come out log2-scaled -> exp2

__device__ __forceinline__ unsigned short f2bf(float f) {
    unsigned u = __builtin_bit_cast(unsigned, f);
    u += 0x7fffu + ((u >> 16) & 1u);          // RNE
    return (unsigned short)(u >> 16);
}

// pack two f32 -> two bf16 in one dword: round-to-nearest (ties away) + v_perm
__device__ __forceinline__ unsigned pack2bf(float f0, float f1) {
    unsigned u0 = __builtin_bit_cast(unsigned, f0) + 0x8000u;
    unsigned u1 = __builtin_bit_cast(unsigned, f1) + 0x8000u;
    return __builtin_amdgcn_perm(u1, u0, 0x07060302);  // {hi16(u1),hi16(u0)}
}

// pack two f32 -> two bf16 via v_cvt_pk_bf16_f32 (documented HIP intrinsic;
// .x -> low16, .y -> high16 == pack2bf placement, RNE rounding).
// memcpy (not bit_cast): __hip_bfloat162 is not trivially copyable.
__device__ __forceinline__ unsigned pkbf(float a, float b) {
    __hip_bfloat162 h = __float22bfloat162_rn(make_float2(a, b));
    unsigned r;
    __builtin_memcpy(&r, &h, 4);
    return r;
}

// async global->LDS, 16B per lane; LDS dest = wave-uniform base + lane*16
__device__ __forceinline__ void gld16(const void* g, void* l) {
    void* gnc = (void*)g;
    __builtin_amdgcn_global_load_lds((__attribute__((address_space(1))) void*)gnc,
                                     (__attribute__((address_space(3))) void*)l,
                                     16, 0, 0);
}

// swizzled LDS short-offset for (row R, 16B-granule g) in a 64-short-row tile
__device__ __forceinline__ int swz(int R, int g) {
    return R * 64 + ((g ^ (R & 7)) << 3);
}

// ---------------------------------------------------------------- fused casts
__global__ void castall(const float* __restrict__ X, const float* __restrict__ Wq,
                        const float* __restrict__ Wk, const float* __restrict__ Wv,
                        const float* __restrict__ Wo, unsigned short* __restrict__ Xb,
                        unsigned short* __restrict__ Wqkvb, unsigned short* __restrict__ Wob) {
    const int bx = blockIdx.x;
    const float* src; unsigned short* dst; int idx;
    if (bx < 8192) { src = X; dst = Xb; idx = bx * 256 + threadIdx.x; }
    else {
        const int r = bx - 8192, w = r >> 10;
        idx = (r & 1023) * 256 + threadIdx.x;
        src = (w == 0) ? Wq : (w == 1) ? Wk : (w == 2) ? Wv : Wo;
        dst = (w == 3) ? Wob : Wqkvb + (size_t)w * 1048576;
    }
    float4 v = ((const float4*)src)[idx];
    ((uint2*)dst)[idx] = make_uint2(pack2bf(v.x, v.y), pack2bf(v.z, v.w));
}

// ---------------------------------------------------------------- fused QKV GEMM
// A: (8192,1024) bf16. Wqkv: 3 stacked (1024,1024) bf16 = one (3072,1024).
// 128x256 tile (4-phase counted-vmcnt), BK=64, 8 waves (2Mx4N, per-wave
// 64x64, acc[4][4]), 96 KiB LDS dbuf. Grid 768 = 3 balanced rounds.
// Per K-tile t: ph0 read B(8)+A(mf0), stage A(t+1)->b^1; ph1 read A(mf1),
// stage B0(t+2)->b; ph2 read A(mf2), stage B1(t+2)->b; ph3 read A(mf3),
// vmcnt(4). Each phase: barrier; setprio(1); 8 MFMA; setprio(0); barrier.
// XCD swizzle: chunks of 96. Epilogue: Q scaled by QSCALE; V transposed
// per head: Vt[(b*1024+n)*2048+s].
__global__ __launch_bounds__(512, 2) void gemm_qkv(const unsigned short* __restrict__ A,
                                                   const unsigned short* __restrict__ Wqkv,
                                                   const float* __restrict__ bq,
                                                   const float* __restrict__ bk,
                                                   const float* __restrict__ bv,
                                                   unsigned short* __restrict__ Qb,
                                                   unsigned short* __restrict__ Kb,
                                                   unsigned short* __restrict__ Vt) {
    __shared__ alignas(16) unsigned short smem[49152];   // 96 KiB: [buf][A 128x64|B 256x64]

    const int tid  = threadIdx.x;
    const int lane = tid & 63;
    const int w    = tid >> 6;
    const int quad = lane >> 4;
    const int l15  = lane & 15;
    const int lr   = lane >> 3;
    const int lcs  = (((lane & 7) ^ lr) << 3);
    const int wm   = w >> 2;            // 0..1 (M, 64 rows each)
    const int wn   = w & 3;             // 0..3 (N, 64 cols each)

    // XCD swizzle: 768 blocks, 768%8==0 -> wg=(orig&7)*96+orig>>3.
    int wg = blockIdx.x;
    wg = (wg & 7) * 96 + (wg >> 3);
    const int nn = wg % 12, mm = wg / 12;
    const int col0 = nn * 256;           // within 3072 (QKV stacked)
    const int row0 = mm * 128;           // token row

    const unsigned short* aS = A    + (size_t)(row0 + w * 16 + lr) * 1024 + lcs;
    const unsigned short* bS = Wqkv + (size_t)(col0 + w * 16 + lr) * 1024 + lcs;
    const int dstW = w * 1024;

#define STG_AQ(t_, b_)                                                                  \
    { const unsigned short* s_ = aS + (t_) * 64;                                        \
      gld16(s_,            &smem[(b_) * 24576 + dstW]);                                 \
      gld16(s_ + 8 * 1024, &smem[(b_) * 24576 + dstW + 512]); }
#define STG_BQ(t_, h_, b_)                                                              \
    { const unsigned short* s_ = bS + (size_t)(h_) * 131072 + (t_) * 64;                \
      gld16(s_,            &smem[(b_) * 24576 + 8192 + (h_) * 8192 + dstW]);            \
      gld16(s_ + 8 * 1024, &smem[(b_) * 24576 + 8192 + (h_) * 8192 + dstW + 512]); }

    f32x4 acc[4][4];
#pragma unroll
    for (int i = 0; i < 4; i++)
#pragma unroll
        for (int j = 0; j < 4; j++) acc[i][j] = f32x4{0.f, 0.f, 0.f, 0.f};

    // prologue: tile0 fully (A,B0,B1) + tile1's B halves; wait tile0.
    STG_AQ(0, 0) STG_BQ(0, 0, 0) STG_BQ(0, 1, 0)
    STG_BQ(1, 0, 1) STG_BQ(1, 1, 1)
    asm volatile("s_waitcnt vmcnt(4)" ::: "memory");
    __builtin_amdgcn_s_barrier();

    for (int t = 0; t < 16; ++t) {
        const int b = t & 1;
        unsigned short* bufA = smem + b * 24576;
        unsigned short* bufB = bufA + 8192;
        bf16x8 bfr[4][2];
#pragma unroll
        for (int p = 0; p < 4; ++p) {
            bf16x8 afr[2];
            if (p == 0) {
#pragma unroll
                for (int nf = 0; nf < 4; ++nf)
#pragma unroll
                    for (int kx = 0; kx < 2; ++kx)
                        bfr[nf][kx] = *(const bf16x8*)&bufB[swz(wn * 64 + nf * 16 + l15, kx * 4 + quad)];
            }
#pragma unroll
            for (int kx = 0; kx < 2; ++kx)
                afr[kx] = *(const bf16x8*)&bufA[swz(wm * 64 + p * 16 + l15, kx * 4 + quad)];

            if (p == 0)      { if (t < 15) STG_AQ(t + 1, b ^ 1) }
            else if (p == 1) { if (t < 14) STG_BQ(t + 2, 0, b) }
            else if (p == 2) { if (t < 14) STG_BQ(t + 2, 1, b) }
            else {
                if (t < 14)      { asm volatile("s_waitcnt vmcnt(4)" ::: "memory"); }
                else if (t == 14){ asm volatile("s_waitcnt vmcnt(0)" ::: "memory"); }
            }
            __builtin_amdgcn_s_barrier();
            __builtin_amdgcn_s_setprio(1);
#pragma unroll
            for (int kx = 0; kx < 2; ++kx)
#pragma unroll
                for (int nf = 0; nf < 4; ++nf)
                    acc[p][nf] = __builtin_amdgcn_mfma_f32_16x16x32_bf16(
                        afr[kx], bfr[nf][kx], acc[p][nf], 0, 0, 0);
            __builtin_amdgcn_s_setprio(0);
            __builtin_amdgcn_s_barrier();
        }
    }
#undef STG_AQ
#undef STG_BQ

    // ---- epilogue: bounce through dead staging LDS for coalesced b128 stores
    const int nb   = col0 >> 10;             // 0=Q 1=K 2=V
    const int colq = col0 & 1023;
    const float* bias = (nb == 0) ? bq : (nb == 1) ? bk : bv;

    if (nb != 2) {
        const float sc = (nb == 0) ? QSCALE : 1.0f;
        unsigned short* C = (nb == 0) ? Qb : Kb;
        // OT[128][264]: all 8 waves write their 64x64 quadrants
#pragma unroll
        for (int mf = 0; mf < 4; ++mf)
#pragma unroll
            for (int nf = 0; nf < 4; ++nf) {
                const int ct  = wn * 64 + nf * 16 + l15;
                const float bvv = bias[colq + ct];
                const int rt  = wm * 64 + mf * 16 + quad * 4;
#pragma unroll
                for (int r = 0; r < 4; ++r)
                    smem[(rt + r) * 264 + ct] = f2bf((acc[mf][nf][r] + bvv) * sc);
            }
        __syncthreads();
        const int rr = tid >> 2, qq = tid & 3;
        unsigned short* gdst = C + (size_t)(row0 + rr) * 1024 + colq + qq * 64;
#pragma unroll
        for (int j = 0; j < 8; ++j)
            *(bf16x8*)(gdst + j * 8) = *(const bf16x8*)&smem[rr * 264 + qq * 64 + j * 8];
    } else {
        const int bb = row0 >> 11, s0 = row0 & 2047;
        // OT[256 d][136 s]: transposed tile (s range = 128 rows)
#pragma unroll
        for (int mf = 0; mf < 4; ++mf)
#pragma unroll
            for (int nf = 0; nf < 4; ++nf) {
                const int ct  = wn * 64 + nf * 16 + l15;
                const float bvv = bias[colq + ct];
                const int st  = wm * 64 + mf * 16 + quad * 4;
                *(uint2*)&smem[ct * 136 + st] =
                    make_uint2(pack2bf(acc[mf][nf][0] + bvv, acc[mf][nf][1] + bvv),
                               pack2bf(acc[mf][nf][2] + bvv, acc[mf][nf][3] + bvv));
            }
        __syncthreads();
        const int c = tid >> 1, hs = tid & 1;
        unsigned short* gdst = Vt + ((size_t)(bb * 1024 + colq + c)) * 2048 + s0 + hs * 64;
#pragma unroll
        for (int j = 0; j < 8; ++j)
            *(bf16x8*)(gdst + j * 8) = *(const bf16x8*)&smem[c * 136 + hs * 64 + j * 8];
    }
}

// ---------------------------------------------------------------- out GEMM (f32 out)
// gemm 4-phase counted-vmcnt structure. BM=128 x BN=256, BK=64, 8 waves
// (2Mx4N, per-wave 64x64, acc[4][4]), 96 KiB LDS dbuf, grid 256 = 1 block/CU.
__global__ __launch_bounds__(512, 2) void gemm_out(const unsigned short* __restrict__ A,
                                                   const unsigned short* __restrict__ W,
                                                   const float* __restrict__ bias,
                                                   float* __restrict__ C) {
    __shared__ alignas(16) unsigned short smem[49152];   // 96 KiB: [buf][A 128x64|B 256x64]

    const int tid  = threadIdx.x;
    const int lane = tid & 63;
    const int w    = tid >> 6;
    const int quad = lane >> 4;
    const int l15  = lane & 15;
    const int lr   = lane >> 3;
    const int lcs  = (((lane & 7) ^ lr) << 3);
    const int wm   = w >> 2;            // 0..1 (M, 64 rows each)
    const int wn   = w & 3;             // 0..3 (N, 64 cols each)

    // XCD swizzle: 256 blocks -> wg=(orig&7)*32+orig>>3; XCD owns 8 M-panels.
    int wg = blockIdx.x;
    wg = (wg & 7) * 32 + (wg >> 3);
    const int col0 = (wg & 3) * 256;     // N tile (4)
    const int row0 = (wg >> 2) * 128;    // M tile (64)

    const unsigned short* aS = A + (size_t)(row0 + w * 16 + lr) * 1024 + lcs;
    const unsigned short* bS = W + (size_t)(col0 + w * 16 + lr) * 1024 + lcs;
    const int dstW = w * 1024;

#define STG_AO(t_, b_)                                                                  \
    { const unsigned short* s_ = aS + (t_) * 64;                                        \
      gld16(s_,            &smem[(b_) * 24576 + dstW]);                                 \
      gld16(s_ + 8 * 1024, &smem[(b_) * 24576 + dstW + 512]); }
#define STG_BO(t_, h_, b_)                                                              \
    { const unsigned short* s_ = bS + (size_t)(h_) * 131072 + (t_) * 64;                \
      gld16(s_,            &smem[(b_) * 24576 + 8192 + (h_) * 8192 + dstW]);            \
      gld16(s_ + 8 * 1024, &smem[(b_) * 24576 + 8192 + (h_) * 8192 + dstW + 512]); }

    f32x4 acc[4][4];
#pragma unroll
    for (int i = 0; i < 4; i++)
#pragma unroll
        for (int j = 0; j < 4; j++) acc[i][j] = f32x4{0.f, 0.f, 0.f, 0.f};

    // prologue: tile0 fully (A,B0,B1) + tile1's B halves; wait tile0.
    STG_AO(0, 0) STG_BO(0, 0, 0) STG_BO(0, 1, 0)
    STG_BO(1, 0, 1) STG_BO(1, 1, 1)
    asm volatile("s_waitcnt vmcnt(4)" ::: "memory");
    __builtin_amdgcn_s_barrier();

    for (int t = 0; t < 16; ++t) {
        const int b = t & 1;
        unsigned short* bufA = smem + b * 24576;
        unsigned short* bufB = bufA + 8192;
        bf16x8 bfr[4][2];
#pragma unroll
        for (int p = 0; p < 4; ++p) {
            bf16x8 afr[2];
            if (p == 0) {
#pragma unroll
                for (int nf = 0; nf < 4; ++nf)
#pragma unroll
                    for (int kx = 0; kx < 2; ++kx)
                        bfr[nf][kx] = *(const bf16x8*)&bufB[swz(wn * 64 + nf * 16 + l15, kx * 4 + quad)];
            }
#pragma unroll
            for (int kx = 0; kx < 2; ++kx)
                afr[kx] = *(const bf16x8*)&bufA[swz(wm * 64 + p * 16 + l15, kx * 4 + quad)];

            if (p == 0)      { if (t < 15) STG_AO(t + 1, b ^ 1) }
            else if (p == 1) { if (t < 14) STG_BO(t + 2, 0, b) }
            else if (p == 2) { if (t < 14) STG_BO(t + 2, 1, b) }
            else {
                if (t < 14)      { asm volatile("s_waitcnt vmcnt(4)" ::: "memory"); }
                else if (t == 14){ asm volatile("s_waitcnt vmcnt(0)" ::: "memory"); }
            }
            __builtin_amdgcn_s_barrier();
            __builtin_amdgcn_s_setprio(1);
#pragma unroll
            for (int kx = 0; kx < 2; ++kx)
#pragma unroll
                for (int nf = 0; nf < 4; ++nf)
                    acc[p][nf] = __builtin_amdgcn_mfma_f32_16x16x32_bf16(
                        afr[kx], bfr[nf][kx], acc[p][nf], 0, 0, 0);
            __builtin_amdgcn_s_setprio(0);
            __builtin_amdgcn_s_barrier();
        }
    }
#undef STG_AO
#undef STG_BO

#pragma unroll
    for (int mf = 0; mf < 4; ++mf) {
#pragma unroll
        for (int nf = 0; nf < 4; ++nf) {
            const int col   = col0 + wn * 64 + nf * 16 + l15;
            const float bvv = bias[col];
            const int rbase = row0 + wm * 64 + mf * 16 + quad * 4;
#pragma unroll
            for (int r = 0; r < 4; r++)
                C[(size_t)(rbase + r) * 1024 + col] = acc[mf][nf][r] + bvv;
        }
    }
}

// ---------------------------------------------------------------- flash attention
// Q, K: (B*S, 1024) bf16; Q pre-scaled by QSCALE (fold softmax scale + log2e).
// Vt: (B*1024, 2048) bf16. Ctx out: (B*S, 1024) bf16.
// Block: 256 q-rows of one (b,h), 8 waves (512 thr); wave owns 32 q-rows.
// 32 k-tiles of 64. Pipelined loop: per iteration QK(kt) -> PV(kt-1) ->
// exp/pack(kt). V TRIPLE-buffered, K dbuf. Row-sums via MFMA. Zero-C QK
// MFMA; hoisted offsets; setprio(1) over merged MFMA cluster; cvt_pk packs.
// R12 grid: 1D 512, decode x=wg&7, qt=(wg>>3)&7, g=x+8*(wg>>6), h=g&15,
// b=g>>4. All 8 qt-blocks of one (b,h) have wg==x (mod 8) -> same XCD
// (round-robin dispatch), co-resident (2 blocks/CU) -> shared K/V panels
// (512KB x 8 groups = 4MB = L2) become L2 hits: FETCH 141MB -> ~unique.
__global__ __launch_bounds__(512, 4) void attn(const unsigned short* __restrict__ Q,
                                               const unsigned short* __restrict__ K,
                                               const unsigned short* __restrict__ Vt,
                                               unsigned short* __restrict__ Ctx) {
    __shared__ alignas(16) unsigned short Kl[2][4096];     // K dbuf (16KB), swizzled
    __shared__ alignas(16) unsigned short Vl[3][4096];     // V tbuf (24KB), swizzled
    __shared__ alignas(16) unsigned short Pl[8][2048];     // per-wave [32 q][64 k] swz (32KB)

    const int tid  = threadIdx.x;
    const int lane = tid & 63;
    const int wave = tid >> 6;        // 0..7
    const int quad = lane >> 4;
    const int l15  = lane & 15;
    const int lr   = lane >> 3;
    const int lcs  = (((lane & 7) ^ lr) << 3);

    // XCD-locality decode (bijective on [0,512))
    const int wg = blockIdx.x;
    const int qt = (wg >> 3) & 7;
    const int g8 = (wg & 7) | ((wg >> 6) << 3);   // group = h + 16*b, 0..63
    const int h  = g8 & 15;
    const int b  = g8 >> 4;
    const int q0 = qt * 256;
    const size_t tokbase = (size_t)b * 2048;

    // hoisted swizzled LDS offsets: frag (nt,kx) at [nt*1024 + lo(kx)];
    // P A-frag (mt,kx) at [mt*1024 + lo(kx)] in the wave's Pl tile.
    const int lo0 = l15 * 64 + (((quad    ) ^ (l15 & 7)) << 3);
    const int lo1 = l15 * 64 + (((quad + 4) ^ (l15 & 7)) << 3);
    // P write offset for k-block nt (b64 = 4 shorts at col nt*16+quad*4):
    int pwoff[4];
#pragma unroll
    for (int nt = 0; nt < 4; ++nt)
        pwoff[nt] = l15 * 64 + ((((nt << 1) | (quad >> 1)) ^ (l15 & 7)) << 3) + ((quad & 1) << 2);
    unsigned short* pw = &Pl[wave][0];

    // staging source base pointers (advance by constant per kt)
    const int rr = wave * 8 + lr;
    const unsigned short* kp = K  + (tokbase + rr) * 1024 + h * 64 + lcs;
    const unsigned short* vp = Vt + ((size_t)(b * 1024 + h * 64 + rr)) * 2048 + lcs;

    bf16x8 qa[2][2];
#pragma unroll
    for (int mt = 0; mt < 2; ++mt)
#pragma unroll
        for (int kx = 0; kx < 2; ++kx)
            qa[mt][kx] = *(const bf16x8*)(Q + (tokbase + q0 + wave * 32 + mt * 16 + l15) * 1024 +
                                          h * 64 + kx * 32 + quad * 8);

    f32x4 O[2][4], Osum[2];
#pragma unroll
    for (int mt = 0; mt < 2; ++mt) {
#pragma unroll
        for (int nt = 0; nt < 4; ++nt) O[mt][nt] = f32x4{0.f, 0.f, 0.f, 0.f};
        Osum[mt] = f32x4{0.f, 0.f, 0.f, 0.f};
    }
    const f32x4 z4 = {0.f, 0.f, 0.f, 0.f};   // persistent zero C-operand
    const bf16x8 vones = {16256, 16256, 16256, 16256, 16256, 16256, 16256, 16256};  // bf16 1.0

#define AT_STAGE(kt_, kb_, vbuf_)                                                               \
    {                                                                                           \
        gld16(kp + (size_t)(kt_) * 65536, &Kl[kb_][wave * 512]);                                \
        gld16(vp + (kt_) * 64,            &Vl[vbuf_][wave * 512]);                              \
    }

// QK(kt): S^T = K @ Q^T  (C layout: row=quad*4+r is K-COL, col=lane&15 is Q-ROW)
#define QK_BLOCK(kbase_)                                                                        \
    {                                                                                           \
        bf16x8 kb[4];                                                                           \
        _Pragma("unroll") for (int nt = 0; nt < 4; ++nt)                                        \
            kb[nt] = *(const bf16x8*)&(kbase_)[lo0 + nt * 1024];                                \
        _Pragma("unroll") for (int nt = 0; nt < 4; ++nt)                                        \
            _Pragma("unroll") for (int mt = 0; mt < 2; ++mt)                                    \
                St[nt][mt] = __builtin_amdgcn_mfma_f32_16x16x32_bf16(kb[nt], qa[mt][0], z4, 0, 0, 0); \
        _Pragma("unroll") for (int nt = 0; nt < 4; ++nt)                                        \
            kb[nt] = *(const bf16x8*)&(kbase_)[lo1 + nt * 1024];                                \
        _Pragma("unroll") for (int nt = 0; nt < 4; ++nt)                                        \
            _Pragma("unroll") for (int mt = 0; mt < 2; ++mt)                                    \
                St[nt][mt] = __builtin_amdgcn_mfma_f32_16x16x32_bf16(kb[nt], qa[mt][1], St[nt][mt], 0, 0, 0); \
    }

// PV(prev): O += P @ V ; Osum += P @ ones  (pa from pw, vb from vbase_)
#define PV_BLOCK(vbase_)                                                                        \
    _Pragma("unroll") for (int kx = 0; kx < 2; ++kx) {                                          \
        bf16x8 pa[2], vb[4];                                                                    \
        _Pragma("unroll") for (int mt = 0; mt < 2; ++mt)                                        \
            pa[mt] = *(const bf16x8*)&pw[mt * 1024 + (kx ? lo1 : lo0)];                         \
        _Pragma("unroll") for (int nt = 0; nt < 4; ++nt)                                        \
            vb[nt] = *(const bf16x8*)&(vbase_)[(kx ? lo1 : lo0) + nt * 1024];                   \
        _Pragma("unroll") for (int mt = 0; mt < 2; ++mt) {                                      \
            _Pragma("unroll") for (int nt = 0; nt < 4; ++nt)                                    \
                O[mt][nt] = __builtin_amdgcn_mfma_f32_16x16x32_bf16(pa[mt], vb[nt], O[mt][nt], 0, 0, 0); \
            Osum[mt] = __builtin_amdgcn_mfma_f32_16x16x32_bf16(pa[mt], vones, Osum[mt], 0, 0, 0); \
        }                                                                                       \
    }

// exp/pack(kt) -> per-wave swizzled P tile (single-inst cvt_pk packs)
#define SM_BLOCK                                                                                \
    _Pragma("unroll") for (int mt = 0; mt < 2; ++mt) {                                          \
        _Pragma("unroll") for (int nt = 0; nt < 4; ++nt) {                                      \
            float p0 = __builtin_amdgcn_exp2f(St[nt][mt][0]);                                   \
            float p1 = __builtin_amdgcn_exp2f(St[nt][mt][1]);                                   \
            float p2 = __builtin_amdgcn_exp2f(St[nt][mt][2]);                                   \
            float p3 = __builtin_amdgcn_exp2f(St[nt][mt][3]);                                   \
            *(uint2*)&pw[mt * 1024 + pwoff[nt]] =                                               \
                make_uint2(pkbf(p0, p1), pkbf(p2, p3));                                         \
        }                                                                                       \
    }

    f32x4 St[4][2];

    // prologue: stage tile0; publish; stage tile1; QK(0)+softmax(0)
    AT_STAGE(0, 0, 0)
    __syncthreads();
    AT_STAGE(1, 1, 1)
    QK_BLOCK(&Kl[0][0])
    SM_BLOCK

    int vprev = 0;   // (kt-1)%3
    int vnext = 2;   // (kt+1)%3
    for (int kt = 1; kt < 32; ++kt) {
        __syncthreads();                 // publishes tile kt; drains prev DS reads
        if (kt < 31) AT_STAGE(kt + 1, (kt + 1) & 1, vnext)
        const unsigned short* kbase = &Kl[kt & 1][0];
        const unsigned short* vbase = &Vl[vprev][0];
        __builtin_amdgcn_s_setprio(1);
        QK_BLOCK(kbase)                  // MFMA: St(kt)
        PV_BLOCK(vbase)                  // MFMA: O += P(kt-1)@V(kt-1); pa reads precede pw writes
        __builtin_amdgcn_s_setprio(0);
        SM_BLOCK                         // VALU: exp/pack(kt) -> pw (St complete by now)
        vprev = (vprev == 2) ? 0 : vprev + 1;
        vnext = (vnext == 2) ? 0 : vnext + 1;
    }
    // epilogue: PV(31) -- P in pw (own wave), V(31) in Vl[vprev=1] (published @kt=31)
    PV_BLOCK(&Vl[vprev][0])

#undef AT_STAGE
#undef QK_BLOCK
#undef PV_BLOCK
#undef SM_BLOCK

    // normalize + store ctx; O C-layout rows = quad*4+r match Osum rows exactly
#pragma unroll
    for (int mt = 0; mt < 2; ++mt) {
#pragma unroll
        for (int r = 0; r < 4; ++r) {
            const float inv = 1.0f / Osum[mt][r];
            const int row   = q0 + wave * 32 + mt * 16 + quad * 4 + r;
            const size_t base = (tokbase + row) * 1024 + h * 64;
#pragma unroll
            for (int nt = 0; nt < 4; ++nt)
                Ctx[base + nt * 16 + l15] = f2bf(O[mt][nt][r] * inv);
        }
    }
}

// ---------------------------------------------------------------- launch
extern "C" void kernel_launch(void* const* d_in, const int* in_sizes, int n_in,
                              void* d_out, int out_size, void* d_ws, size_t ws_size,
                              hipStream_t stream) {
    (void)in_sizes; (void)n_in; (void)out_size; (void)ws_size;
    const float* X  = (const float*)d_in[0];
    const float* Wq = (const float*)d_in[1];
    const float* bq = (const float*)d_in[2];
    const float* Wk = (const float*)d_in[3];
    const float* bk = (const float*)d_in[4];
    const float* Wv = (const float*)d_in[5];
    const float* bv = (const float*)d_in[6];
    const float* Wo = (const float*)d_in[7];
    const float* bo = (const float*)d_in[8];

    char* ws = (char*)d_ws;
    unsigned short* Xb    = (unsigned short*)(ws);                        // 16 MB (aliased as Ctx)
    unsigned short* Qb    = (unsigned short*)(ws + (size_t)16 * 1048576); // 16 MB
    unsigned short* Kb    = (unsigned short*)(ws + (size_t)32 * 1048576); // 16 MB
    unsigned short* Vt    = (unsigned short*)(ws + (size_t)48 * 1048576); // 16 MB
    unsigned short* Wqkvb = (unsigned short*)(ws + (size_t)64 * 1048576); // 6 MB
    unsigned short* Wob   = (unsigned short*)(ws + (size_t)70 * 1048576); // 2 MB
    unsigned short* Ctx   = Xb;  // X dead after QKV GEMM (stream-ordered)

    castall<<<dim3(12288), 256, 0, stream>>>(X, Wq, Wk, Wv, Wo, Xb, Wqkvb, Wob);
    gemm_qkv<<<dim3(768), 512, 0, stream>>>(Xb, Wqkvb, bq, bk, bv, Qb, Kb, Vt);
    attn<<<dim3(512), 512, 0, stream>>>(Qb, Kb, Vt, Ctx);
    gemm_out<<<dim3(256), 512, 0, stream>>>(Ctx, Wob, bo, (float*)d_out);
}